// Round 1
// baseline (626.167 us; speedup 1.0000x reference)
//
#include <hip/hip_runtime.h>

#define N_NODES  200000
#define N_EDGES  3200000
#define HIDDEN   64
#define N_GRAPHS 4096
#define N_CLASSES 7
#define NBUCK    196          // ceil(N_NODES / 1024)
#define BSHIFT   10
#define BMASK    1023

// ---------- coarse histogram (196 buckets) ----------
#define CH_EPT 16
__global__ void k_chist(const int* __restrict__ dst, int* __restrict__ chist) {
    __shared__ int h[NBUCK];
    for (int i = threadIdx.x; i < NBUCK; i += 256) h[i] = 0;
    __syncthreads();
    int base = blockIdx.x * 256 * CH_EPT + threadIdx.x;
    for (int k = 0; k < CH_EPT; ++k) {
        int e = base + k * 256;
        if (e < N_EDGES) atomicAdd(&h[dst[e] >> BSHIFT], 1);
    }
    __syncthreads();
    for (int i = threadIdx.x; i < NBUCK; i += 256) atomicAdd(&chist[i], h[i]);
}

// ---------- scan of 196 bucket counts ----------
__global__ void k_cscan(const int* __restrict__ chist, int* __restrict__ cbase,
                        int* __restrict__ gcur) {
    __shared__ int tmp[256];
    int tid = threadIdx.x;
    int v = (tid < NBUCK) ? chist[tid] : 0;
    int x = v; tmp[tid] = x; __syncthreads();
    for (int o = 1; o < 256; o <<= 1) {
        int y = (tid >= o) ? tmp[tid - o] : 0;
        __syncthreads();
        x += y; tmp[tid] = x;
        __syncthreads();
    }
    if (tid < NBUCK) { cbase[tid] = x - v; gcur[tid] = x - v; }
    if (tid == 0) cbase[NBUCK] = N_EDGES;
}

// ---------- coarse partition: stage[pos] = (src<<10)|(dst&1023) ----------
#define PT_EPT 32
__global__ void k_part(const int* __restrict__ src, const int* __restrict__ dst,
                       int* __restrict__ gcur, int* __restrict__ stage) {
    __shared__ int lh[NBUCK];
    __shared__ int lbase[NBUCK];
    __shared__ int lcur[NBUCK];
    for (int i = threadIdx.x; i < NBUCK; i += 256) { lh[i] = 0; lcur[i] = 0; }
    __syncthreads();
    int base = blockIdx.x * 256 * PT_EPT + threadIdx.x;
    for (int k = 0; k < PT_EPT; ++k) {
        int e = base + k * 256;
        if (e < N_EDGES) atomicAdd(&lh[dst[e] >> BSHIFT], 1);
    }
    __syncthreads();
    for (int i = threadIdx.x; i < NBUCK; i += 256)
        if (lh[i] > 0) lbase[i] = atomicAdd(&gcur[i], lh[i]);
    __syncthreads();
    for (int k = 0; k < PT_EPT; ++k) {
        int e = base + k * 256;
        if (e < N_EDGES) {
            int d = dst[e], b = d >> BSHIFT;
            int lp = atomicAdd(&lcur[b], 1);
            stage[lbase[b] + lp] = (src[e] << BSHIFT) | (d & BMASK);
        }
    }
}

// ---------- per-bucket exact sort + CSR metadata; also prescale x by dinv ----------
__global__ void k_sort(const int* __restrict__ stage, const int* __restrict__ cbase,
                       int* __restrict__ edges, int* __restrict__ off,
                       int* __restrict__ endv, float* __restrict__ dinv,
                       const float2* __restrict__ x2, float2* __restrict__ xs2) {
    __shared__ int hist[1024];
    __shared__ int tmp[256];
    int b = blockIdx.x, tid = threadIdx.x;
    int cb0 = cbase[b], cb1 = cbase[b + 1];
    for (int k = 0; k < 4; ++k) hist[tid * 4 + k] = 0;
    __syncthreads();
    for (int j = cb0 + tid; j < cb1; j += 256)
        atomicAdd(&hist[stage[j] & BMASK], 1);
    __syncthreads();
    int c0 = hist[tid*4], c1 = hist[tid*4+1], c2 = hist[tid*4+2], c3 = hist[tid*4+3];
    int s = c0 + c1 + c2 + c3;
    int x = s; tmp[tid] = x; __syncthreads();
    for (int o = 1; o < 256; o <<= 1) {
        int y = (tid >= o) ? tmp[tid - o] : 0;
        __syncthreads();
        x += y; tmp[tid] = x;
        __syncthreads();
    }
    int run = x - s;                 // exclusive prefix of this thread's 4 counters
    int nbase = b << BSHIFT;
    int counts[4] = {c0, c1, c2, c3};
    for (int k = 0; k < 4; ++k) {
        int v = tid * 4 + k;
        hist[v] = run;               // local cursor start
        int node = nbase + v;
        if (node < N_NODES) {
            off[node]  = cb0 + run;
            endv[node] = cb0 + run + counts[k];
            float di = rsqrtf((float)counts[k] + 1.0f);   // +1 self loop
            dinv[node] = di;
            float2 xv = x2[node];
            xs2[node] = make_float2(di * xv.x, di * xv.y);
        }
        run += counts[k];
    }
    __syncthreads();
    for (int j = cb0 + tid; j < cb1; j += 256) {
        int p = stage[j];
        int pos = atomicAdd(&hist[p & BMASK], 1);
        edges[cb0 + pos] = p >> BSHIFT;     // src
    }
}

static __device__ __forceinline__ float rdlane(float v, int l) {
    return __uint_as_float(__builtin_amdgcn_readlane(__float_as_uint(v), (unsigned)l));
}

// ---------- layer 1: gather prescaled x (2ch, lane-parallel edges) + W1 + relu,
//            then fused transform for layer 2: Yout = dinv * (h1 @ W2) ----------
__global__ __launch_bounds__(256, 4)
void k_l1(const int* __restrict__ edges, const int* __restrict__ off,
          const int* __restrict__ endv, const float* __restrict__ dinv,
          const float2* __restrict__ xs2,
          const float* __restrict__ W1, const float* __restrict__ b1,
          const float* __restrict__ W2, float* __restrict__ Yout) {
    int lane = threadIdx.x & 63;
    int wid = blockIdx.x * (blockDim.x >> 6) + (threadIdx.x >> 6);
    int nw = gridDim.x * (blockDim.x >> 6);
    float w1a = W1[lane], w1b = W1[64 + lane], bb = b1[lane];
    float wcol[64];
#pragma unroll
    for (int k = 0; k < 64; ++k) wcol[k] = W2[k * 64 + lane];
    for (int n = wid; n < N_NODES; n += nw) {
        float dn = dinv[n];
        int j0 = off[n], j1 = endv[n];
        float px = 0.0f, py = 0.0f;
        for (int j = j0 + lane; j < j1; j += 64) {
            float2 v = xs2[edges[j]];
            px += v.x; py += v.y;
        }
#pragma unroll
        for (int o = 1; o < 64; o <<= 1) {
            px += __shfl_xor(px, o, 64);
            py += __shfl_xor(py, o, 64);
        }
        float2 xv = xs2[n];                    // = dn * x[n]
        float gx = dn * (px + xv.x);
        float gy = dn * (py + xv.y);
        float h = gx * w1a + gy * w1b + bb;
        h = h > 0.0f ? h : 0.0f;
        float y = 0.0f;
#pragma unroll
        for (int k = 0; k < 64; ++k) y += rdlane(h, k) * wcol[k];
        Yout[n * 64 + lane] = dn * y;
    }
}

// ---------- layers 2/3: pure-sum gather of prescaled rows (lane-per-channel),
//            bias+relu, then either fused transform (W_next) or final write ----------
template<bool FINAL>
__global__ __launch_bounds__(256, 4)
void k_gl(const int* __restrict__ edges, const int* __restrict__ off,
          const int* __restrict__ endv, const float* __restrict__ dinv,
          const float* __restrict__ Yin, const float* __restrict__ Wn,
          const float* __restrict__ bias, float* __restrict__ Yout) {
    int lane = threadIdx.x & 63;
    int wid = blockIdx.x * (blockDim.x >> 6) + (threadIdx.x >> 6);
    int nw = gridDim.x * (blockDim.x >> 6);
    float bb = bias[lane];
    float wcol[64];
    if (!FINAL) {
#pragma unroll
        for (int k = 0; k < 64; ++k) wcol[k] = Wn[k * 64 + lane];
    }
    for (int n = wid; n < N_NODES; n += nw) {
        float dn = dinv[n];
        int j0 = off[n], j1 = endv[n];
        int deg = j1 - j0;
        float acc = Yin[n * 64 + lane];        // self loop (prescaled)
        int evec = (j0 + lane < j1) ? edges[j0 + lane] : 0;
        int m = deg < 64 ? deg : 64;
        int j = 0;
        for (; j + 4 <= m; j += 4) {
            int s0 = __builtin_amdgcn_readlane(evec, j);
            int s1 = __builtin_amdgcn_readlane(evec, j + 1);
            int s2 = __builtin_amdgcn_readlane(evec, j + 2);
            int s3 = __builtin_amdgcn_readlane(evec, j + 3);
            float v0 = Yin[s0 * 64 + lane];
            float v1 = Yin[s1 * 64 + lane];
            float v2 = Yin[s2 * 64 + lane];
            float v3 = Yin[s3 * 64 + lane];
            acc += v0; acc += v1; acc += v2; acc += v3;
        }
        for (; j < m; ++j) {
            int s = __builtin_amdgcn_readlane(evec, j);
            acc += Yin[s * 64 + lane];
        }
        for (int jj = 64; jj < deg; ++jj) {    // astronomically rare tail (deg > 64)
            int s = edges[j0 + jj];
            acc += Yin[s * 64 + lane];
        }
        float h = dn * acc + bb;
        h = h > 0.0f ? h : 0.0f;
        if (FINAL) {
            Yout[n * 64 + lane] = h;
        } else {
            float y = 0.0f;
#pragma unroll
            for (int k = 0; k < 64; ++k) y += rdlane(h, k) * wcol[k];
            Yout[n * 64 + lane] = dn * y;
        }
    }
}

// ---------- segmented mean-pool accumulation (batch is sorted) ----------
#define PCHUNK 64
__global__ void k_pool(const float* __restrict__ A, const int* __restrict__ batch,
                       float* __restrict__ sums, float* __restrict__ cnts) {
    int c = threadIdx.x;
    int n0 = blockIdx.x * PCHUNK;
    int n1 = n0 + PCHUNK; if (n1 > N_NODES) n1 = N_NODES;
    int gcur = batch[n0];
    float acc = 0.0f;
    int cnt = 0;
    for (int n = n0; n < n1; ++n) {
        int g = batch[n];
        if (g != gcur) {
            atomicAdd(&sums[gcur * 64 + c], acc);
            if (c == 0) atomicAdd(&cnts[gcur], (float)cnt);
            acc = 0.0f; cnt = 0; gcur = g;
        }
        acc += A[n * 64 + c];
        ++cnt;
    }
    atomicAdd(&sums[gcur * 64 + c], acc);
    if (c == 0) atomicAdd(&cnts[gcur], (float)cnt);
}

// ---------- MLP head ----------
__global__ void k_head(const float* __restrict__ sums, const float* __restrict__ cnts,
                       const float* __restrict__ Wf1, const float* __restrict__ bf1,
                       const float* __restrict__ Wf2, const float* __restrict__ bf2,
                       float* __restrict__ out) {
    __shared__ float p[64];
    __shared__ float h[64];
    int g = blockIdx.x;
    int c = threadIdx.x;
    float cnt = cnts[g];
    cnt = cnt > 1.0f ? cnt : 1.0f;
    p[c] = sums[g * 64 + c] / cnt;
    __syncthreads();
    float s = bf1[c];
#pragma unroll
    for (int k = 0; k < 64; ++k) s += p[k] * Wf1[k * 64 + c];
    h[c] = s > 0.0f ? s : 0.0f;
    __syncthreads();
    if (c < N_CLASSES) {
        float o = bf2[c];
#pragma unroll
        for (int k = 0; k < 64; ++k) o += h[k] * Wf2[k * N_CLASSES + c];
        out[g * N_CLASSES + c] = o;
    }
}

extern "C" void kernel_launch(void* const* d_in, const int* in_sizes, int n_in,
                              void* d_out, int out_size, void* d_ws, size_t ws_size,
                              hipStream_t stream) {
    const float* x   = (const float*)d_in[0];
    const int*   ei  = (const int*)d_in[1];
    const int*   bat = (const int*)d_in[2];
    const float* W1  = (const float*)d_in[3];
    const float* b1  = (const float*)d_in[4];
    const float* W2  = (const float*)d_in[5];
    const float* b2  = (const float*)d_in[6];
    const float* W3  = (const float*)d_in[7];
    const float* b3  = (const float*)d_in[8];
    const float* Wf1 = (const float*)d_in[9];
    const float* bf1 = (const float*)d_in[10];
    const float* Wf2 = (const float*)d_in[11];
    const float* bf2 = (const float*)d_in[12];
    float* out = (float*)d_out;

    const int* src = ei;
    const int* dst = ei + N_EDGES;

    char* p = (char*)d_ws;
    float* P     = (float*)p;   p += (size_t)N_NODES * 64 * 4;
    float* Q     = (float*)p;   p += (size_t)N_NODES * 64 * 4;
    int*   stage = (int*)p;     p += (size_t)N_EDGES * 4;
    int*   edges = (int*)p;     p += (size_t)N_EDGES * 4;
    int*   off   = (int*)p;     p += (size_t)N_NODES * 4;
    int*   endv  = (int*)p;     p += (size_t)N_NODES * 4;
    float* dinv  = (float*)p;   p += (size_t)N_NODES * 4;
    float* xs2   = (float*)p;   p += (size_t)N_NODES * 2 * 4;
    int*   chist = (int*)p;     p += (size_t)256 * 4;
    int*   cbase = (int*)p;     p += (size_t)256 * 4;
    int*   gcur  = (int*)p;     p += (size_t)256 * 4;
    float* sums  = (float*)p;   p += (size_t)N_GRAPHS * 64 * 4;
    float* cnts  = (float*)p;   p += (size_t)N_GRAPHS * 4;

    hipMemsetAsync(chist, 0, 256 * 4, stream);
    hipMemsetAsync(sums, 0, (size_t)(N_GRAPHS * 64 + N_GRAPHS) * 4, stream);

    const int BT = 256;
    int gChist = (N_EDGES + 256 * CH_EPT - 1) / (256 * CH_EPT);   // 782
    int gPart  = (N_EDGES + 256 * PT_EPT - 1) / (256 * PT_EPT);   // 391

    // ---- CSR build (binned, no global scatter over full buffer) ----
    k_chist<<<gChist, BT, 0, stream>>>(dst, chist);
    k_cscan<<<1, 256, 0, stream>>>(chist, cbase, gcur);
    k_part<<<gPart, BT, 0, stream>>>(src, dst, gcur, stage);
    k_sort<<<NBUCK, 256, 0, stream>>>(stage, cbase, edges, off, endv, dinv,
                                      (const float2*)x, (float2*)xs2);

    // ---- layer 1 (gather x, W1, relu, fused W2 transform + prescale) ----
    k_l1<<<1024, BT, 0, stream>>>(edges, off, endv, dinv, (const float2*)xs2,
                                  W1, b1, W2, P);

    // ---- layer 2 (pure-sum gather + b2/relu + fused W3 transform + prescale) ----
    k_gl<false><<<1024, BT, 0, stream>>>(edges, off, endv, dinv, P, W3, b2, Q);

    // ---- layer 3 (pure-sum gather + b3/relu, final activations) ----
    k_gl<true><<<2048, BT, 0, stream>>>(edges, off, endv, dinv, Q, nullptr, b3, P);

    // ---- pool + head ----
    k_pool<<<(N_NODES + PCHUNK - 1) / PCHUNK, 64, 0, stream>>>(P, bat, sums, cnts);
    k_head<<<N_GRAPHS, 64, 0, stream>>>(sums, cnts, Wf1, bf1, Wf2, bf2, out);
}

// Round 3
// 581.805 us; speedup vs baseline: 1.0762x; 1.0762x over previous
//
#include <hip/hip_runtime.h>

#define N_NODES  200000
#define N_EDGES  3200000
#define HIDDEN   64
#define N_GRAPHS 4096
#define N_CLASSES 7
#define NBUCK    196          // ceil(N_NODES / 1024)
#define BSHIFT   10
#define BMASK    1023
#define CPW      16           // nodes (chunk) per wave
#define NCHUNK   (N_NODES / CPW)          // 12500
#define GLAYER   (NCHUNK / 4)             // 3125 blocks of 4 waves

// ---------- coarse histogram (196 buckets) ----------
#define CH_EPT 16
__global__ void k_chist(const int* __restrict__ dst, int* __restrict__ chist) {
    __shared__ int h[NBUCK];
    for (int i = threadIdx.x; i < NBUCK; i += 256) h[i] = 0;
    __syncthreads();
    int base = blockIdx.x * 256 * CH_EPT + threadIdx.x;
    for (int k = 0; k < CH_EPT; ++k) {
        int e = base + k * 256;
        if (e < N_EDGES) atomicAdd(&h[dst[e] >> BSHIFT], 1);
    }
    __syncthreads();
    for (int i = threadIdx.x; i < NBUCK; i += 256) atomicAdd(&chist[i], h[i]);
}

// ---------- scan of 196 bucket counts ----------
__global__ void k_cscan(const int* __restrict__ chist, int* __restrict__ cbase,
                        int* __restrict__ gcur) {
    __shared__ int tmp[256];
    int tid = threadIdx.x;
    int v = (tid < NBUCK) ? chist[tid] : 0;
    int x = v; tmp[tid] = x; __syncthreads();
    for (int o = 1; o < 256; o <<= 1) {
        int y = (tid >= o) ? tmp[tid - o] : 0;
        __syncthreads();
        x += y; tmp[tid] = x;
        __syncthreads();
    }
    if (tid < NBUCK) { cbase[tid] = x - v; gcur[tid] = x - v; }
    if (tid == 0) cbase[NBUCK] = N_EDGES;
}

// ---------- coarse partition: stage[pos] = (src<<10)|(dst&1023) ----------
#define PT_EPT 32
__global__ void k_part(const int* __restrict__ src, const int* __restrict__ dst,
                       int* __restrict__ gcur, int* __restrict__ stage) {
    __shared__ int lh[NBUCK];
    __shared__ int lbase[NBUCK];
    __shared__ int lcur[NBUCK];
    for (int i = threadIdx.x; i < NBUCK; i += 256) { lh[i] = 0; lcur[i] = 0; }
    __syncthreads();
    int base = blockIdx.x * 256 * PT_EPT + threadIdx.x;
    for (int k = 0; k < PT_EPT; ++k) {
        int e = base + k * 256;
        if (e < N_EDGES) atomicAdd(&lh[dst[e] >> BSHIFT], 1);
    }
    __syncthreads();
    for (int i = threadIdx.x; i < NBUCK; i += 256)
        if (lh[i] > 0) lbase[i] = atomicAdd(&gcur[i], lh[i]);
    __syncthreads();
    for (int k = 0; k < PT_EPT; ++k) {
        int e = base + k * 256;
        if (e < N_EDGES) {
            int d = dst[e], b = d >> BSHIFT;
            int lp = atomicAdd(&lcur[b], 1);
            stage[lbase[b] + lp] = (src[e] << BSHIFT) | (d & BMASK);
        }
    }
}

// ---------- per-bucket exact sort + CSR metadata; also prescale x by dinv ----------
__global__ void k_sort(const int* __restrict__ stage, const int* __restrict__ cbase,
                       int* __restrict__ edges, int* __restrict__ off,
                       int* __restrict__ endv, float* __restrict__ dinv,
                       const float2* __restrict__ x2, float2* __restrict__ xs2) {
    __shared__ int hist[1024];
    __shared__ int tmp[256];
    int b = blockIdx.x, tid = threadIdx.x;
    int cb0 = cbase[b], cb1 = cbase[b + 1];
    for (int k = 0; k < 4; ++k) hist[tid * 4 + k] = 0;
    __syncthreads();
    for (int j = cb0 + tid; j < cb1; j += 256)
        atomicAdd(&hist[stage[j] & BMASK], 1);
    __syncthreads();
    int c0 = hist[tid*4], c1 = hist[tid*4+1], c2 = hist[tid*4+2], c3 = hist[tid*4+3];
    int s = c0 + c1 + c2 + c3;
    int x = s; tmp[tid] = x; __syncthreads();
    for (int o = 1; o < 256; o <<= 1) {
        int y = (tid >= o) ? tmp[tid - o] : 0;
        __syncthreads();
        x += y; tmp[tid] = x;
        __syncthreads();
    }
    int run = x - s;                 // exclusive prefix of this thread's 4 counters
    int nbase = b << BSHIFT;
    int counts[4] = {c0, c1, c2, c3};
    for (int k = 0; k < 4; ++k) {
        int v = tid * 4 + k;
        hist[v] = run;               // local cursor start
        int node = nbase + v;
        if (node < N_NODES) {
            off[node]  = cb0 + run;
            endv[node] = cb0 + run + counts[k];
            float di = rsqrtf((float)counts[k] + 1.0f);   // +1 self loop
            dinv[node] = di;
            float2 xv = x2[node];
            xs2[node] = make_float2(di * xv.x, di * xv.y);
        }
        run += counts[k];
    }
    __syncthreads();
    for (int j = cb0 + tid; j < cb1; j += 256) {
        int p = stage[j];
        int pos = atomicAdd(&hist[p & BMASK], 1);
        edges[cb0 + pos] = p >> BSHIFT;     // src
    }
}

static __device__ __forceinline__ float rdlf(float v, int l) {
    return __uint_as_float(__builtin_amdgcn_readlane(__float_as_uint(v), (unsigned)l));
}
static __device__ __forceinline__ int rdli(int v, int l) {
    return __builtin_amdgcn_readlane(v, (unsigned)l);
}

// ---------- layer 1: chunked gather of prescaled x + W1 + relu + fused W2 ----------
__global__ __launch_bounds__(256, 4)
void k_l1(const int* __restrict__ edges, const int* __restrict__ off,
          const int* __restrict__ endv, const float* __restrict__ dinv,
          const float2* __restrict__ xs2,
          const float* __restrict__ W1, const float* __restrict__ b1,
          const float* __restrict__ W2, float* __restrict__ Yout) {
    int lane = threadIdx.x & 63;
    int wid = blockIdx.x * 4 + (threadIdx.x >> 6);
    int n0 = wid * CPW;
    if (n0 >= N_NODES) return;
    float w1a = W1[lane], w1b = W1[64 + lane], bb = b1[lane];
    float4 wc[16];
#pragma unroll
    for (int q = 0; q < 16; ++q) {
        wc[q].x = W2[(4 * q + 0) * 64 + lane];
        wc[q].y = W2[(4 * q + 1) * 64 + lane];
        wc[q].z = W2[(4 * q + 2) * 64 + lane];
        wc[q].w = W2[(4 * q + 3) * 64 + lane];
    }
    // chunk metadata in lanes 0..15
    int mo = 0, me = 0; float md = 0.0f; float sxx = 0.0f, sxy = 0.0f;
    if (lane < CPW) {
        int nn = n0 + lane;
        mo = off[nn]; me = endv[nn]; md = dinv[nn];
        float2 sv = xs2[nn];
        sxx = sv.x; sxy = sv.y;
    }
    int j0 = rdli(mo, 0);
    int idx = j0 + lane; if (idx > N_EDGES - 1) idx = N_EDGES - 1;
    int ev = edges[idx];
    for (int i = 0; i < CPW; ++i) {
        int n = n0 + i;
        int j1 = rdli(me, i);
        float dn = rdlf(md, i);
        int deg = j1 - j0;
        int evn = 0; int j0n = 0;
        if (i < CPW - 1) {
            j0n = rdli(mo, i + 1);
            int idn = j0n + lane; if (idn > N_EDGES - 1) idn = N_EDGES - 1;
            evn = edges[idn];
        }
        float px = 0.0f, py = 0.0f;
        if (lane < deg) {                       // deg <= 64 (typ. ~16)
            float2 v = xs2[ev];
            px = v.x; py = v.y;
        }
        for (int jj = j0 + 64 + lane; jj < j1; jj += 64) {   // rare deg>64 tail
            float2 v = xs2[edges[jj]];
            px += v.x; py += v.y;
        }
#pragma unroll
        for (int o = 1; o < 64; o <<= 1) {
            px += __shfl_xor(px, o, 64);
            py += __shfl_xor(py, o, 64);
        }
        float gx = dn * (px + rdlf(sxx, i));
        float gy = dn * (py + rdlf(sxy, i));
        float h = gx * w1a + gy * w1b + bb;
        h = h > 0.0f ? h : 0.0f;
        float y0 = 0.0f, y1 = 0.0f, y2 = 0.0f, y3 = 0.0f;
#pragma unroll
        for (int q = 0; q < 16; ++q) {
            float4 w = wc[q];
            y0 = fmaf(rdlf(h, 4 * q + 0), w.x, y0);
            y1 = fmaf(rdlf(h, 4 * q + 1), w.y, y1);
            y2 = fmaf(rdlf(h, 4 * q + 2), w.z, y2);
            y3 = fmaf(rdlf(h, 4 * q + 3), w.w, y3);
        }
        Yout[n * 64 + lane] = dn * ((y0 + y1) + (y2 + y3));
        ev = evn; j0 = j0n;
    }
}

// ---------- layers 2/3: chunked pure-sum gather + bias/relu (+ fused W_next) ----------
template<bool FINAL>
__global__ __launch_bounds__(256, 4)
void k_gl(const int* __restrict__ edges, const int* __restrict__ off,
          const int* __restrict__ endv, const float* __restrict__ dinv,
          const float* __restrict__ Yin, const float* __restrict__ Wn,
          const float* __restrict__ bias, float* __restrict__ Yout) {
    int lane = threadIdx.x & 63;
    int wid = blockIdx.x * 4 + (threadIdx.x >> 6);
    int n0 = wid * CPW;
    if (n0 >= N_NODES) return;
    float bb = bias[lane];
    float4 wc[16];
    if (!FINAL) {
#pragma unroll
        for (int q = 0; q < 16; ++q) {
            wc[q].x = Wn[(4 * q + 0) * 64 + lane];
            wc[q].y = Wn[(4 * q + 1) * 64 + lane];
            wc[q].z = Wn[(4 * q + 2) * 64 + lane];
            wc[q].w = Wn[(4 * q + 3) * 64 + lane];
        }
    }
    // chunk metadata in lanes 0..15
    int mo = 0, me = 0; float md = 0.0f;
    if (lane < CPW) {
        int nn = n0 + lane;
        mo = off[nn]; me = endv[nn]; md = dinv[nn];
    }
    int j0 = rdli(mo, 0);
    int idx = j0 + lane; if (idx > N_EDGES - 1) idx = N_EDGES - 1;
    int ev = edges[idx];                         // edge-index vector, node 0
    float sacc = Yin[n0 * 64 + lane];            // self row, node 0
    for (int i = 0; i < CPW; ++i) {
        int n = n0 + i;
        int j1 = rdli(me, i);
        float dn = rdlf(md, i);
        int deg = j1 - j0;
        int evn = 0; float snext = 0.0f; int j0n = 0;
        if (i < CPW - 1) {                       // prefetch next node's vectors
            j0n = rdli(mo, i + 1);
            int idn = j0n + lane; if (idn > N_EDGES - 1) idn = N_EDGES - 1;
            evn = edges[idn];
            snext = Yin[(n + 1) * 64 + lane];
        }
        float acc = sacc, acc2 = 0.0f;
        int m = deg < 64 ? deg : 64;
        int j = 0;
        for (; j + 8 <= m; j += 8) {
            int s0 = rdli(ev, j + 0), s1 = rdli(ev, j + 1);
            int s2 = rdli(ev, j + 2), s3 = rdli(ev, j + 3);
            int s4 = rdli(ev, j + 4), s5 = rdli(ev, j + 5);
            int s6 = rdli(ev, j + 6), s7 = rdli(ev, j + 7);
            float v0 = Yin[s0 * 64 + lane];
            float v1 = Yin[s1 * 64 + lane];
            float v2 = Yin[s2 * 64 + lane];
            float v3 = Yin[s3 * 64 + lane];
            float v4 = Yin[s4 * 64 + lane];
            float v5 = Yin[s5 * 64 + lane];
            float v6 = Yin[s6 * 64 + lane];
            float v7 = Yin[s7 * 64 + lane];
            acc += v0; acc2 += v1; acc += v2; acc2 += v3;
            acc += v4; acc2 += v5; acc += v6; acc2 += v7;
        }
        for (; j < m; ++j) {
            int s = rdli(ev, j);
            acc += Yin[s * 64 + lane];
        }
        for (int jj = 64; jj < deg; ++jj) {      // rare deg>64 tail
            int s = edges[j0 + jj];
            acc2 += Yin[s * 64 + lane];
        }
        float h = dn * (acc + acc2) + bb;
        h = h > 0.0f ? h : 0.0f;
        if (FINAL) {
            Yout[n * 64 + lane] = h;
        } else {
            float y0 = 0.0f, y1 = 0.0f, y2 = 0.0f, y3 = 0.0f;
#pragma unroll
            for (int q = 0; q < 16; ++q) {
                float4 w = wc[q];
                y0 = fmaf(rdlf(h, 4 * q + 0), w.x, y0);
                y1 = fmaf(rdlf(h, 4 * q + 1), w.y, y1);
                y2 = fmaf(rdlf(h, 4 * q + 2), w.z, y2);
                y3 = fmaf(rdlf(h, 4 * q + 3), w.w, y3);
            }
            Yout[n * 64 + lane] = dn * ((y0 + y1) + (y2 + y3));
        }
        ev = evn; sacc = snext; j0 = j0n;
    }
}

// ---------- segmented mean-pool accumulation (batch is sorted) ----------
#define PCHUNK 64
__global__ void k_pool(const float* __restrict__ A, const int* __restrict__ batch,
                       float* __restrict__ sums, float* __restrict__ cnts) {
    int c = threadIdx.x;
    int n0 = blockIdx.x * PCHUNK;
    int n1 = n0 + PCHUNK; if (n1 > N_NODES) n1 = N_NODES;
    int gcur = batch[n0];
    float acc = 0.0f;
    int cnt = 0;
    for (int n = n0; n < n1; ++n) {
        int g = batch[n];
        if (g != gcur) {
            atomicAdd(&sums[gcur * 64 + c], acc);
            if (c == 0) atomicAdd(&cnts[gcur], (float)cnt);
            acc = 0.0f; cnt = 0; gcur = g;
        }
        acc += A[n * 64 + c];
        ++cnt;
    }
    atomicAdd(&sums[gcur * 64 + c], acc);
    if (c == 0) atomicAdd(&cnts[gcur], (float)cnt);
}

// ---------- MLP head ----------
__global__ void k_head(const float* __restrict__ sums, const float* __restrict__ cnts,
                       const float* __restrict__ Wf1, const float* __restrict__ bf1,
                       const float* __restrict__ Wf2, const float* __restrict__ bf2,
                       float* __restrict__ out) {
    __shared__ float p[64];
    __shared__ float h[64];
    int g = blockIdx.x;
    int c = threadIdx.x;
    float cnt = cnts[g];
    cnt = cnt > 1.0f ? cnt : 1.0f;
    p[c] = sums[g * 64 + c] / cnt;
    __syncthreads();
    float s = bf1[c];
#pragma unroll
    for (int k = 0; k < 64; ++k) s += p[k] * Wf1[k * 64 + c];
    h[c] = s > 0.0f ? s : 0.0f;
    __syncthreads();
    if (c < N_CLASSES) {
        float o = bf2[c];
#pragma unroll
        for (int k = 0; k < 64; ++k) o += h[k] * Wf2[k * N_CLASSES + c];
        out[g * N_CLASSES + c] = o;
    }
}

extern "C" void kernel_launch(void* const* d_in, const int* in_sizes, int n_in,
                              void* d_out, int out_size, void* d_ws, size_t ws_size,
                              hipStream_t stream) {
    const float* x   = (const float*)d_in[0];
    const int*   ei  = (const int*)d_in[1];
    const int*   bat = (const int*)d_in[2];
    const float* W1  = (const float*)d_in[3];
    const float* b1  = (const float*)d_in[4];
    const float* W2  = (const float*)d_in[5];
    const float* b2  = (const float*)d_in[6];
    const float* W3  = (const float*)d_in[7];
    const float* b3  = (const float*)d_in[8];
    const float* Wf1 = (const float*)d_in[9];
    const float* bf1 = (const float*)d_in[10];
    const float* Wf2 = (const float*)d_in[11];
    const float* bf2 = (const float*)d_in[12];
    float* out = (float*)d_out;

    const int* src = ei;
    const int* dst = ei + N_EDGES;

    char* p = (char*)d_ws;
    float* P     = (float*)p;   p += (size_t)N_NODES * 64 * 4;
    float* Q     = (float*)p;   p += (size_t)N_NODES * 64 * 4;
    int*   stage = (int*)p;     p += (size_t)N_EDGES * 4;
    int*   edges = (int*)p;     p += (size_t)N_EDGES * 4;
    int*   off   = (int*)p;     p += (size_t)N_NODES * 4;
    int*   endv  = (int*)p;     p += (size_t)N_NODES * 4;
    float* dinv  = (float*)p;   p += (size_t)N_NODES * 4;
    float* xs2   = (float*)p;   p += (size_t)N_NODES * 2 * 4;
    int*   chist = (int*)p;     p += (size_t)256 * 4;
    int*   cbase = (int*)p;     p += (size_t)256 * 4;
    int*   gcur  = (int*)p;     p += (size_t)256 * 4;
    float* sums  = (float*)p;   p += (size_t)N_GRAPHS * 64 * 4;
    float* cnts  = (float*)p;   p += (size_t)N_GRAPHS * 4;

    hipMemsetAsync(chist, 0, 256 * 4, stream);
    hipMemsetAsync(sums, 0, (size_t)(N_GRAPHS * 64 + N_GRAPHS) * 4, stream);

    const int BT = 256;
    int gChist = (N_EDGES + 256 * CH_EPT - 1) / (256 * CH_EPT);   // 782
    int gPart  = (N_EDGES + 256 * PT_EPT - 1) / (256 * PT_EPT);   // 391

    // ---- CSR build (binned, no global scatter over full buffer) ----
    k_chist<<<gChist, BT, 0, stream>>>(dst, chist);
    k_cscan<<<1, 256, 0, stream>>>(chist, cbase, gcur);
    k_part<<<gPart, BT, 0, stream>>>(src, dst, gcur, stage);
    k_sort<<<NBUCK, 256, 0, stream>>>(stage, cbase, edges, off, endv, dinv,
                                      (const float2*)x, (float2*)xs2);

    // ---- layer 1 (gather x, W1, relu, fused W2 transform + prescale) ----
    k_l1<<<GLAYER, BT, 0, stream>>>(edges, off, endv, dinv, (const float2*)xs2,
                                    W1, b1, W2, P);

    // ---- layer 2 (pure-sum gather + b2/relu + fused W3 transform + prescale) ----
    k_gl<false><<<GLAYER, BT, 0, stream>>>(edges, off, endv, dinv, P, W3, b2, Q);

    // ---- layer 3 (pure-sum gather + b3/relu, final activations) ----
    k_gl<true><<<GLAYER, BT, 0, stream>>>(edges, off, endv, dinv, Q, nullptr, b3, P);

    // ---- pool + head ----
    k_pool<<<(N_NODES + PCHUNK - 1) / PCHUNK, 64, 0, stream>>>(P, bat, sums, cnts);
    k_head<<<N_GRAPHS, 64, 0, stream>>>(sums, cnts, Wf1, bf1, Wf2, bf2, out);
}

// Round 6
// 567.267 us; speedup vs baseline: 1.1038x; 1.0256x over previous
//
#include <hip/hip_runtime.h>

#define N_NODES  200000
#define N_EDGES  3200000
#define HIDDEN   64
#define N_GRAPHS 4096
#define N_CLASSES 7
#define NBUCK    196          // ceil(N_NODES / 1024)
#define BSHIFT   10
#define BMASK    1023
#define CPW      16           // nodes (chunk) per wave
#define NCHUNK   (N_NODES / CPW)          // 12500
#define GLAYER   (NCHUNK / 4)             // 3125 blocks of 4 waves

// ---------- coarse histogram (196 buckets) ----------
#define CH_EPT 16
__global__ void k_chist(const int* __restrict__ dst, int* __restrict__ chist) {
    __shared__ int h[NBUCK];
    for (int i = threadIdx.x; i < NBUCK; i += 256) h[i] = 0;
    __syncthreads();
    int base = blockIdx.x * 256 * CH_EPT + threadIdx.x;
    for (int k = 0; k < CH_EPT; ++k) {
        int e = base + k * 256;
        if (e < N_EDGES) atomicAdd(&h[dst[e] >> BSHIFT], 1);
    }
    __syncthreads();
    for (int i = threadIdx.x; i < NBUCK; i += 256) atomicAdd(&chist[i], h[i]);
}

// ---------- scan of 196 bucket counts ----------
__global__ void k_cscan(const int* __restrict__ chist, int* __restrict__ cbase,
                        int* __restrict__ gcur) {
    __shared__ int tmp[256];
    int tid = threadIdx.x;
    int v = (tid < NBUCK) ? chist[tid] : 0;
    int x = v; tmp[tid] = x; __syncthreads();
    for (int o = 1; o < 256; o <<= 1) {
        int y = (tid >= o) ? tmp[tid - o] : 0;
        __syncthreads();
        x += y; tmp[tid] = x;
        __syncthreads();
    }
    if (tid < NBUCK) { cbase[tid] = x - v; gcur[tid] = x - v; }
    if (tid == 0) cbase[NBUCK] = N_EDGES;
}

// ---------- coarse partition: stage[pos] = (src<<10)|(dst&1023) ----------
#define PT_EPT 32
__global__ void k_part(const int* __restrict__ src, const int* __restrict__ dst,
                       int* __restrict__ gcur, int* __restrict__ stage) {
    __shared__ int lh[NBUCK];
    __shared__ int lbase[NBUCK];
    __shared__ int lcur[NBUCK];
    for (int i = threadIdx.x; i < NBUCK; i += 256) { lh[i] = 0; lcur[i] = 0; }
    __syncthreads();
    int base = blockIdx.x * 256 * PT_EPT + threadIdx.x;
    for (int k = 0; k < PT_EPT; ++k) {
        int e = base + k * 256;
        if (e < N_EDGES) atomicAdd(&lh[dst[e] >> BSHIFT], 1);
    }
    __syncthreads();
    for (int i = threadIdx.x; i < NBUCK; i += 256)
        if (lh[i] > 0) lbase[i] = atomicAdd(&gcur[i], lh[i]);
    __syncthreads();
    for (int k = 0; k < PT_EPT; ++k) {
        int e = base + k * 256;
        if (e < N_EDGES) {
            int d = dst[e], b = d >> BSHIFT;
            int lp = atomicAdd(&lcur[b], 1);
            stage[lbase[b] + lp] = (src[e] << BSHIFT) | (d & BMASK);
        }
    }
}

// ---------- per-bucket exact sort + CSR metadata; also prescale x by dinv ----------
__global__ void k_sort(const int* __restrict__ stage, const int* __restrict__ cbase,
                       int* __restrict__ edges, int* __restrict__ off,
                       int* __restrict__ endv, float* __restrict__ dinv,
                       const float2* __restrict__ x2, float2* __restrict__ xs2) {
    __shared__ int hist[1024];
    __shared__ int tmp[256];
    int b = blockIdx.x, tid = threadIdx.x;
    int cb0 = cbase[b], cb1 = cbase[b + 1];
    for (int k = 0; k < 4; ++k) hist[tid * 4 + k] = 0;
    __syncthreads();
    for (int j = cb0 + tid; j < cb1; j += 256)
        atomicAdd(&hist[stage[j] & BMASK], 1);
    __syncthreads();
    int c0 = hist[tid*4], c1 = hist[tid*4+1], c2 = hist[tid*4+2], c3 = hist[tid*4+3];
    int s = c0 + c1 + c2 + c3;
    int x = s; tmp[tid] = x; __syncthreads();
    for (int o = 1; o < 256; o <<= 1) {
        int y = (tid >= o) ? tmp[tid - o] : 0;
        __syncthreads();
        x += y; tmp[tid] = x;
        __syncthreads();
    }
    int run = x - s;                 // exclusive prefix of this thread's 4 counters
    int nbase = b << BSHIFT;
    int counts[4] = {c0, c1, c2, c3};
    for (int k = 0; k < 4; ++k) {
        int v = tid * 4 + k;
        hist[v] = run;               // local cursor start
        int node = nbase + v;
        if (node < N_NODES) {
            off[node]  = cb0 + run;
            endv[node] = cb0 + run + counts[k];
            float di = rsqrtf((float)counts[k] + 1.0f);   // +1 self loop
            dinv[node] = di;
            float2 xv = x2[node];
            xs2[node] = make_float2(di * xv.x, di * xv.y);
        }
        run += counts[k];
    }
    __syncthreads();
    for (int j = cb0 + tid; j < cb1; j += 256) {
        int p = stage[j];
        int pos = atomicAdd(&hist[p & BMASK], 1);
        edges[cb0 + pos] = p >> BSHIFT;     // src
    }
}

static __device__ __forceinline__ float rdlf(float v, int l) {
    return __uint_as_float(__builtin_amdgcn_readlane(__float_as_uint(v), (unsigned)l));
}
static __device__ __forceinline__ int rdli(int v, int l) {
    return __builtin_amdgcn_readlane(v, (unsigned)l);
}

// ---------- layer 1: chunked gather of prescaled x + W1 + relu + fused W2 ----------
__global__ __launch_bounds__(256, 4)
void k_l1(const int* __restrict__ edges, const int* __restrict__ off,
          const int* __restrict__ endv, const float* __restrict__ dinv,
          const float2* __restrict__ xs2,
          const float* __restrict__ W1, const float* __restrict__ b1,
          const float* __restrict__ W2, float* __restrict__ Yout) {
    int lane = threadIdx.x & 63;
    int wid = blockIdx.x * 4 + (threadIdx.x >> 6);
    int n0 = wid * CPW;
    if (n0 >= N_NODES) return;
    float w1a = W1[lane], w1b = W1[64 + lane], bb = b1[lane];
    float4 wc[16];
#pragma unroll
    for (int t = 0; t < 16; ++t) {
        wc[t].x = W2[(4 * t + 0) * 64 + lane];
        wc[t].y = W2[(4 * t + 1) * 64 + lane];
        wc[t].z = W2[(4 * t + 2) * 64 + lane];
        wc[t].w = W2[(4 * t + 3) * 64 + lane];
    }
#pragma unroll
    for (int t = 0; t < 16; ++t) {   // pin W columns in VGPRs (no remat)
        asm volatile("" : "+v"(wc[t].x), "+v"(wc[t].y), "+v"(wc[t].z), "+v"(wc[t].w));
    }
    // chunk metadata in lanes 0..15
    int mo = 0, me = 0; float md = 0.0f; float sxx = 0.0f, sxy = 0.0f;
    if (lane < CPW) {
        int nn = n0 + lane;
        mo = off[nn]; me = endv[nn]; md = dinv[nn];
        float2 sv = xs2[nn];
        sxx = sv.x; sxy = sv.y;
    }
    int j0 = rdli(mo, 0);
    int idx = j0 + lane; if (idx > N_EDGES - 1) idx = N_EDGES - 1;
    int ev = edges[idx];
    for (int i = 0; i < CPW; ++i) {
        int n = n0 + i;
        int j1 = rdli(me, i);
        float dn = rdlf(md, i);
        int deg = j1 - j0;
        int evn = 0; int j0n = 0;
        if (i < CPW - 1) {
            j0n = rdli(mo, i + 1);
            int idn = j0n + lane; if (idn > N_EDGES - 1) idn = N_EDGES - 1;
            evn = edges[idn];
        }
        float px = 0.0f, py = 0.0f;
        if (lane < deg) {                       // deg <= 64 (typ. ~16)
            float2 v = xs2[ev];
            px = v.x; py = v.y;
        }
        for (int jj = j0 + 64 + lane; jj < j1; jj += 64) {   // rare deg>64 tail
            float2 v = xs2[edges[jj]];
            px += v.x; py += v.y;
        }
#pragma unroll
        for (int o = 1; o < 64; o <<= 1) {
            px += __shfl_xor(px, o, 64);
            py += __shfl_xor(py, o, 64);
        }
        float gx = dn * (px + rdlf(sxx, i));
        float gy = dn * (py + rdlf(sxy, i));
        float h = gx * w1a + gy * w1b + bb;
        h = h > 0.0f ? h : 0.0f;
        float y0 = 0.0f, y1 = 0.0f, y2 = 0.0f, y3 = 0.0f;
#pragma unroll
        for (int t = 0; t < 16; ++t) {
            float4 w = wc[t];
            y0 = fmaf(rdlf(h, 4 * t + 0), w.x, y0);
            y1 = fmaf(rdlf(h, 4 * t + 1), w.y, y1);
            y2 = fmaf(rdlf(h, 4 * t + 2), w.z, y2);
            y3 = fmaf(rdlf(h, 4 * t + 3), w.w, y3);
        }
        Yout[n * 64 + lane] = dn * ((y0 + y1) + (y2 + y3));
        ev = evn; j0 = j0n;
    }
}

// ---------- layers 2/3: quad-row gather (4 rows per wave-load) + bias/relu
//            (+ fused W_next transform via readlane) ----------
template<bool FINAL>
__global__ __launch_bounds__(256, 4)
void k_gl(const int* __restrict__ edges, const int* __restrict__ off,
          const int* __restrict__ endv, const float* __restrict__ dinv,
          const float* __restrict__ Yin, const float* __restrict__ Wn,
          const float* __restrict__ bias, float* __restrict__ Yout) {
    const float4* __restrict__ Yin4 = (const float4*)Yin;
    int lane = threadIdx.x & 63;
    int q = lane & 15, s = lane >> 4;          // sub-group: s = which row of a quad
    int wid = blockIdx.x * 4 + (threadIdx.x >> 6);
    int n0 = wid * CPW;
    if (n0 >= N_NODES) return;
    float bb = bias[lane];
    float4 wc[16];
    if (!FINAL) {
#pragma unroll
        for (int t = 0; t < 16; ++t) {
            wc[t].x = Wn[(4 * t + 0) * 64 + lane];
            wc[t].y = Wn[(4 * t + 1) * 64 + lane];
            wc[t].z = Wn[(4 * t + 2) * 64 + lane];
            wc[t].w = Wn[(4 * t + 3) * 64 + lane];
        }
#pragma unroll
        for (int t = 0; t < 16; ++t) {  // pin W columns in VGPRs (no remat)
            asm volatile("" : "+v"(wc[t].x), "+v"(wc[t].y), "+v"(wc[t].z), "+v"(wc[t].w));
        }
    }
    // chunk metadata in lanes 0..15
    int mo = 0, me = 0; float md = 0.0f;
    if (lane < CPW) {
        int nn = n0 + lane;
        mo = off[nn]; me = endv[nn]; md = dinv[nn];
    }
    int j0 = rdli(mo, 0);
    int idx = j0 + lane; if (idx > N_EDGES - 1) idx = N_EDGES - 1;
    int ev = edges[idx];                         // edge-index vector, node 0
    float4 sacc = make_float4(0.f, 0.f, 0.f, 0.f);
    if (s == 0) sacc = Yin4[(size_t)n0 * 16 + q];   // self row (prescaled), sub 0 only
    for (int i = 0; i < CPW; ++i) {
        int n = n0 + i;
        int j1 = rdli(me, i);
        float dn = rdlf(md, i);
        int deg = j1 - j0;
        int evn = 0; int j0n = 0;
        float4 snext = make_float4(0.f, 0.f, 0.f, 0.f);
        if (i < CPW - 1) {                       // prefetch next node's vectors
            j0n = rdli(mo, i + 1);
            int idn = j0n + lane; if (idn > N_EDGES - 1) idn = N_EDGES - 1;
            evn = edges[idn];
            if (s == 0) snext = Yin4[(size_t)(n + 1) * 16 + q];
        }
        float4 acc = sacc;
        int m = deg < 64 ? deg : 64;
        int t = 0;
        int fq4 = (m >> 2) & ~3;                 // full quads, multiple of 4
        for (; t < fq4; t += 4) {
            int i0 = __shfl(ev, 4 * t + s, 64);
            int i1 = __shfl(ev, 4 * t + 4 + s, 64);
            int i2 = __shfl(ev, 4 * t + 8 + s, 64);
            int i3 = __shfl(ev, 4 * t + 12 + s, 64);
            float4 v0 = Yin4[(size_t)i0 * 16 + q];
            float4 v1 = Yin4[(size_t)i1 * 16 + q];
            float4 v2 = Yin4[(size_t)i2 * 16 + q];
            float4 v3 = Yin4[(size_t)i3 * 16 + q];
            acc.x += v0.x; acc.y += v0.y; acc.z += v0.z; acc.w += v0.w;
            acc.x += v1.x; acc.y += v1.y; acc.z += v1.z; acc.w += v1.w;
            acc.x += v2.x; acc.y += v2.y; acc.z += v2.z; acc.w += v2.w;
            acc.x += v3.x; acc.y += v3.y; acc.z += v3.z; acc.w += v3.w;
        }
        for (; 4 * t < m; t += 2) {              // masked tail, 2-wide
            int e0 = 4 * t + s;
            int i0 = __shfl(ev, e0, 64);
            float4 v0 = Yin4[(size_t)i0 * 16 + q];
            if (e0 < m) { acc.x += v0.x; acc.y += v0.y; acc.z += v0.z; acc.w += v0.w; }
            if (4 * (t + 1) < m) {               // wave-uniform guard
                int e1 = 4 * t + 4 + s;
                int i1 = __shfl(ev, e1, 64);
                float4 v1 = Yin4[(size_t)i1 * 16 + q];
                if (e1 < m) { acc.x += v1.x; acc.y += v1.y; acc.z += v1.z; acc.w += v1.w; }
            }
        }
        for (int jj = 64; jj < deg; ++jj) {      // rare deg>64 tail (sub 0 only)
            int sidx = edges[j0 + jj];
            if (s == 0) {
                float4 v = Yin4[(size_t)sidx * 16 + q];
                acc.x += v.x; acc.y += v.y; acc.z += v.z; acc.w += v.w;
            }
        }
        // combine the 4 sub-groups
        acc.x += __shfl_xor(acc.x, 16, 64); acc.x += __shfl_xor(acc.x, 32, 64);
        acc.y += __shfl_xor(acc.y, 16, 64); acc.y += __shfl_xor(acc.y, 32, 64);
        acc.z += __shfl_xor(acc.z, 16, 64); acc.z += __shfl_xor(acc.z, 32, 64);
        acc.w += __shfl_xor(acc.w, 16, 64); acc.w += __shfl_xor(acc.w, 32, 64);
        // redistribute: channel-per-lane layout
        int srcl = lane >> 2;
        float c0 = __shfl(acc.x, srcl, 64);
        float c1 = __shfl(acc.y, srcl, 64);
        float c2 = __shfl(acc.z, srcl, 64);
        float c3 = __shfl(acc.w, srcl, 64);
        float lo = (lane & 1) ? c1 : c0;
        float hi = (lane & 1) ? c3 : c2;
        float sumc = (lane & 2) ? hi : lo;
        float h = dn * sumc + bb;
        h = h > 0.0f ? h : 0.0f;
        if (FINAL) {
            Yout[n * 64 + lane] = h;
        } else {
            float y0 = 0.0f, y1 = 0.0f, y2 = 0.0f, y3 = 0.0f;
#pragma unroll
            for (int t2 = 0; t2 < 16; ++t2) {
                float4 w = wc[t2];
                y0 = fmaf(rdlf(h, 4 * t2 + 0), w.x, y0);
                y1 = fmaf(rdlf(h, 4 * t2 + 1), w.y, y1);
                y2 = fmaf(rdlf(h, 4 * t2 + 2), w.z, y2);
                y3 = fmaf(rdlf(h, 4 * t2 + 3), w.w, y3);
            }
            Yout[n * 64 + lane] = dn * ((y0 + y1) + (y2 + y3));
        }
        ev = evn; sacc = snext; j0 = j0n;
    }
}

// ---------- segmented mean-pool accumulation (batch is sorted) ----------
#define PCHUNK 64
__global__ void k_pool(const float* __restrict__ A, const int* __restrict__ batch,
                       float* __restrict__ sums, float* __restrict__ cnts) {
    int c = threadIdx.x;
    int n0 = blockIdx.x * PCHUNK;
    int n1 = n0 + PCHUNK; if (n1 > N_NODES) n1 = N_NODES;
    int gcur = batch[n0];
    float acc = 0.0f;
    int cnt = 0;
    for (int n = n0; n < n1; ++n) {
        int g = batch[n];
        if (g != gcur) {
            atomicAdd(&sums[gcur * 64 + c], acc);
            if (c == 0) atomicAdd(&cnts[gcur], (float)cnt);
            acc = 0.0f; cnt = 0; gcur = g;
        }
        acc += A[n * 64 + c];
        ++cnt;
    }
    atomicAdd(&sums[gcur * 64 + c], acc);
    if (c == 0) atomicAdd(&cnts[gcur], (float)cnt);
}

// ---------- MLP head ----------
__global__ void k_head(const float* __restrict__ sums, const float* __restrict__ cnts,
                       const float* __restrict__ Wf1, const float* __restrict__ bf1,
                       const float* __restrict__ Wf2, const float* __restrict__ bf2,
                       float* __restrict__ out) {
    __shared__ float p[64];
    __shared__ float h[64];
    int g = blockIdx.x;
    int c = threadIdx.x;
    float cnt = cnts[g];
    cnt = cnt > 1.0f ? cnt : 1.0f;
    p[c] = sums[g * 64 + c] / cnt;
    __syncthreads();
    float s = bf1[c];
#pragma unroll
    for (int k = 0; k < 64; ++k) s += p[k] * Wf1[k * 64 + c];
    h[c] = s > 0.0f ? s : 0.0f;
    __syncthreads();
    if (c < N_CLASSES) {
        float o = bf2[c];
#pragma unroll
        for (int k = 0; k < 64; ++k) o += h[k] * Wf2[k * N_CLASSES + c];
        out[g * N_CLASSES + c] = o;
    }
}

extern "C" void kernel_launch(void* const* d_in, const int* in_sizes, int n_in,
                              void* d_out, int out_size, void* d_ws, size_t ws_size,
                              hipStream_t stream) {
    const float* x   = (const float*)d_in[0];
    const int*   ei  = (const int*)d_in[1];
    const int*   bat = (const int*)d_in[2];
    const float* W1  = (const float*)d_in[3];
    const float* b1  = (const float*)d_in[4];
    const float* W2  = (const float*)d_in[5];
    const float* b2  = (const float*)d_in[6];
    const float* W3  = (const float*)d_in[7];
    const float* b3  = (const float*)d_in[8];
    const float* Wf1 = (const float*)d_in[9];
    const float* bf1 = (const float*)d_in[10];
    const float* Wf2 = (const float*)d_in[11];
    const float* bf2 = (const float*)d_in[12];
    float* out = (float*)d_out;

    const int* src = ei;
    const int* dst = ei + N_EDGES;

    char* p = (char*)d_ws;
    float* P     = (float*)p;   p += (size_t)N_NODES * 64 * 4;
    float* Q     = (float*)p;   p += (size_t)N_NODES * 64 * 4;
    int*   stage = (int*)p;     p += (size_t)N_EDGES * 4;
    int*   edges = (int*)p;     p += (size_t)N_EDGES * 4;
    int*   off   = (int*)p;     p += (size_t)N_NODES * 4;
    int*   endv  = (int*)p;     p += (size_t)N_NODES * 4;
    float* dinv  = (float*)p;   p += (size_t)N_NODES * 4;
    float* xs2   = (float*)p;   p += (size_t)N_NODES * 2 * 4;
    int*   chist = (int*)p;     p += (size_t)256 * 4;
    int*   cbase = (int*)p;     p += (size_t)256 * 4;
    int*   gcur  = (int*)p;     p += (size_t)256 * 4;
    float* sums  = (float*)p;   p += (size_t)N_GRAPHS * 64 * 4;
    float* cnts  = (float*)p;   p += (size_t)N_GRAPHS * 4;

    hipMemsetAsync(chist, 0, 256 * 4, stream);
    hipMemsetAsync(sums, 0, (size_t)(N_GRAPHS * 64 + N_GRAPHS) * 4, stream);

    const int BT = 256;
    int gChist = (N_EDGES + 256 * CH_EPT - 1) / (256 * CH_EPT);   // 782
    int gPart  = (N_EDGES + 256 * PT_EPT - 1) / (256 * PT_EPT);   // 391

    // ---- CSR build (binned, no global scatter over full buffer) ----
    k_chist<<<gChist, BT, 0, stream>>>(dst, chist);
    k_cscan<<<1, 256, 0, stream>>>(chist, cbase, gcur);
    k_part<<<gPart, BT, 0, stream>>>(src, dst, gcur, stage);
    k_sort<<<NBUCK, 256, 0, stream>>>(stage, cbase, edges, off, endv, dinv,
                                      (const float2*)x, (float2*)xs2);

    // ---- layer 1 (gather x, W1, relu, fused W2 transform + prescale) ----
    k_l1<<<GLAYER, BT, 0, stream>>>(edges, off, endv, dinv, (const float2*)xs2,
                                    W1, b1, W2, P);

    // ---- layer 2 (quad gather + b2/relu + fused W3 transform + prescale) ----
    k_gl<false><<<GLAYER, BT, 0, stream>>>(edges, off, endv, dinv, P, W3, b2, Q);

    // ---- layer 3 (quad gather + b3/relu, final activations) ----
    k_gl<true><<<GLAYER, BT, 0, stream>>>(edges, off, endv, dinv, Q, nullptr, b3, P);

    // ---- pool + head ----
    k_pool<<<(N_NODES + PCHUNK - 1) / PCHUNK, 64, 0, stream>>>(P, bat, sums, cnts);
    k_head<<<N_GRAPHS, 64, 0, stream>>>(sums, cnts, Wf1, bf1, Wf2, bf2, out);
}